// Round 10
// baseline (583.938 us; speedup 1.0000x reference)
//
#include <hip/hip_runtime.h>
#include <cmath>

#define NS 64
#define NN 128
#define NT 1000
#define CH 8                                // steps per obuf half-buffer
#define NNP 129                             // padded flush-row stride (bank-free)
#define WROWS 130                           // 128 rows of w + 2 zero rows
#define WL_DW (WROWS * NN)                  // 16640
#define OB_HALF (3 * CH * NNP)              // 3096 dwords per half-buffer
#define OBUF_DW (2 * OB_HALF)               // 6192
#define SPV_DW (2 * NN)                     // 256: [parity][neuron] softplus(v)
#define LDS_BYTES ((WL_DW + OBUF_DW + SPV_DW) * 4)   // 92352

// == npy_logaddexpf(x, 0), branch-free but bit-identical:
//   x>0: fmax=x, |x|=x  -> x + log1p(exp(-x)) ; x<0: 0 + log1p(exp(x)) ; x==0 -> LOGE2
__device__ __forceinline__ float softplus_np(float x) {
    float r = fmaxf(x, 0.0f) + log1pf(expf(-fabsf(x)));
    return (x == 0.0f) ? 0.693147180559945309f : r;
}

// Barrier WITHOUT the compiler's vmcnt(0) drain: LDS-visibility only.
__device__ __forceinline__ void sync_lds() {
    __builtin_amdgcn_sched_barrier(0);
    asm volatile("s_waitcnt lgkmcnt(0)" ::: "memory");
    __builtin_amdgcn_s_barrier();
    __builtin_amdgcn_sched_barrier(0);
}

__global__ __launch_bounds__(192) void snn_scan_kernel(
    const float* __restrict__ w,
    const float* __restrict__ ic,
    const float* __restrict__ v0,
    const float* __restrict__ i0,
    const float* __restrict__ s0,
    const float* __restrict__ mu,
    const float* __restrict__ sigma,
    const float* __restrict__ noise,      // [T, S, N, 2]
    const float* __restrict__ exp_draws,  // [T, S, N]
    float* __restrict__ out)              // [S, N, T, 3]
{
    #pragma clang fp contract(off)
    extern __shared__ float smem[];
    float* wl     = smem;                 // [130][128]: w rows + 2 zero rows
    float* obuf   = smem + WL_DW;         // [2][3*CH][NNP] output staging
    float* spvbuf = smem + WL_DW + OBUF_DW;   // [2][128] softplus(v) exchange

    const int samp = blockIdx.x;
    const int tid  = threadIdx.x;
    const int wid  = tid >> 6;            // waves 0,1 = compute; wave 2 = flush
    const int l    = tid & 63;
    const int n    = (wid << 6) | l;      // own neuron (waves 0,1)
    const int nm   = n ^ 64;              // mirror neuron (other wave's lane l)

    if (tid < 128) {                      // stage w + zero rows (one-time)
        const float4* src = (const float4*)w;
        float4* dst = (float4*)wl;
        #pragma unroll
        for (int it = 0; it < 32; ++it)
            dst[it * 128 + tid] = src[it * 128 + tid];
        ((float2*)(wl + NN * NN))[tid] = make_float2(0.0f, 0.0f);
    }

    const float SQDT  = sqrtf(0.01f);     // 0x3DCCCCCD == np.sqrt(float32(0.01))
    const float DTf   = 0.01f;
    const float LOGE2 = 0.693147180559945309f;

    float* outb = out + (size_t)samp * NN * NT * 3;

    float mu1 = 0.f, negmu2 = 0.f, g00 = 0.f, g01 = 0.f, g10 = 0.f, g11 = 0.f;
    float icn = 0.f, v_ = 0.f, i_ = 0.f, s_ = 0.f, sp = 0.f;
    float s_m = 0.f, spvm_pend = 0.f;     // mirror s-state + pending spv read
    bool  km_prev = false;
    float2 nb0 = {}, nb1 = {}, nb2 = {}, nb3 = {}, nb4 = {}, nb5 = {}, nb6 = {}, nb7 = {};
    float  eo0 = 0, eo1 = 0, eo2 = 0, eo3 = 0, eo4 = 0, eo5 = 0, eo6 = 0, eo7 = 0;
    float  em0 = 0, em1 = 0, em2 = 0, em3 = 0, em4 = 0, em5 = 0, em6 = 0, em7 = 0;

    const float* nzb = noise + (size_t)samp * (NN * 2) + n * 2;   // + t*NS*NN*2
    const float* edo = exp_draws + (size_t)samp * NN + n;         // + t*NS*NN
    const float* edm = exp_draws + (size_t)samp * NN + nm;        // mirror stream

    if (wid < 2) {
        __builtin_amdgcn_s_setprio(1);    // compute waves own the critical path
        mu1 = mu[0]; negmu2 = -mu[1];
        g00 = sigma[0]; g01 = sigma[1]; g10 = sigma[2]; g11 = sigma[3];
        icn = ic[n];
        v_ = v0[samp * NN + n];
        i_ = i0[samp * NN + n];
        s_ = s0[samp * NN + n];
        sp = softplus_np(v_);
        s_m = s0[samp * NN + nm];
        spvm_pend = softplus_np(v0[samp * NN + nm]);   // km_prev=false selects this
        nb0 = *(const float2*)(nzb + 0ull * (NS * NN * 2)); eo0 = edo[0ull * (NS * NN)]; em0 = edm[0ull * (NS * NN)];
        nb1 = *(const float2*)(nzb + 1ull * (NS * NN * 2)); eo1 = edo[1ull * (NS * NN)]; em1 = edm[1ull * (NS * NN)];
        nb2 = *(const float2*)(nzb + 2ull * (NS * NN * 2)); eo2 = edo[2ull * (NS * NN)]; em2 = edm[2ull * (NS * NN)];
        nb3 = *(const float2*)(nzb + 3ull * (NS * NN * 2)); eo3 = edo[3ull * (NS * NN)]; em3 = edm[3ull * (NS * NN)];
        nb4 = *(const float2*)(nzb + 4ull * (NS * NN * 2)); eo4 = edo[4ull * (NS * NN)]; em4 = edm[4ull * (NS * NN)];
        nb5 = *(const float2*)(nzb + 5ull * (NS * NN * 2)); eo5 = edo[5ull * (NS * NN)]; em5 = edm[5ull * (NS * NN)];
        nb6 = *(const float2*)(nzb + 6ull * (NS * NN * 2)); eo6 = edo[6ull * (NS * NN)]; em6 = edm[6ull * (NS * NN)];
        nb7 = *(const float2*)(nzb + 7ull * (NS * NN * 2)); eo7 = edo[7ull * (NS * NN)]; em7 = edm[7ull * (NS * NN)];
    }
    sync_lds();                           // w + zero rows visible

    if (wid < 2) {
        // ---------------- compute waves ----------------
        auto STEP = [&](int k, int blk, float2& nb, float& eo, float& em) {
            #pragma clang fp contract(off)
            const int t = blk * CH + k;
            const int par = k & 1;        // t&1 == k&1 (CH even)
            // --- own s-chain: mask ASAP
            s_ = s_ + DTf * sp;
            const bool kk = (s_ >= 0.0f);
            const unsigned long long mown = __ballot(kk);
            // --- consume prefetch, reissue t+8 (clamped)
            const float2 nz = nb; const float edv = eo; const float edmv = em;
            const int tp = (t + CH) < NT ? (t + CH) : NT - 1;
            nb = *(const float2*)(nzb + (size_t)tp * (NS * NN * 2));
            eo = edo[(size_t)tp * (NS * NN)];
            em = edm[(size_t)tp * (NS * NN)];
            // --- drift + noise (independent of masks)
            const float dw0 = nz.x * SQDT, dw1 = nz.y * SQDT;
            const float nv = (dw0 * g00) + (dw1 * g01);
            const float ni = (dw0 * g10) + (dw1 * g11);
            const float tt = (i_ + icn) - v_;
            const float vt = (v_ + DTf * (mu1 * tt)) + nv;
            const float it = (i_ + DTf * (negmu2 * i_)) + ni;
            const float spv = softplus_np(vt);
            spvbuf[par * NN + n] = spv;   // publish for the other wave
            // --- mirror s-chain (deferred select hides last step's LDS read)
            const float spm = km_prev ? LOGE2 : spvm_pend;
            s_m = s_m + DTf * spm;
            const bool kmir = (s_m >= 0.0f);
            const unsigned long long mmir = __ballot(kmir);
            // --- both masks known locally: coupling
            unsigned long long m0 = (wid == 0) ? mown : mmir;   // neurons 0..63
            unsigned long long m1 = (wid == 0) ? mmir : mown;   // neurons 64..127
            float a = 0.0f;
            if (m0 | m1) {
                auto ext1 = [&]() -> int {    // ascending order: drain m0 then m1
                    const bool u0 = (m0 != 0);
                    const unsigned long long m = u0 ? m0 : m1;
                    const int b = m ? (int)__builtin_ctzll(m) : 99;
                    const int r = (b == 99) ? 128 : ((u0 ? 0 : 64) + b);
                    const unsigned long long m0n = m0 & (m0 - 1);
                    const unsigned long long m1n = m1 & (m1 - 1);
                    m0 = u0 ? m0n : m0;
                    m1 = u0 ? m1 : m1n;
                    return r;             // empty -> zero row 128 (+0.0 exact)
                };
                const int r1 = ext1(); const int r2 = ext1();
                const int r3 = ext1(); const int r4 = ext1();
                const float q1 = wl[r1 * NN + n];   // 4 independent ds_read_b32
                const float q2 = wl[r2 * NN + n];
                const float q3 = wl[r3 * NN + n];
                const float q4 = wl[r4 * NN + n];
                a = q1;  a += q2;  a += q3;  a += q4;   // ascending fp32 sum
                #pragma clang loop unroll(disable)
                while (m0 | m1) {                     // >=5 spikes: rare
                    const int r = ext1();
                    a += wl[r * NN + n];
                }
            }
            i_ = it + a;                  // unconditional add: bit-identical
            v_ = kk ? 0.0f : vt;
            s_ = kk ? -edv : s_;
            sp = kk ? LOGE2 : spv;
            s_m = kmir ? -edmv : s_m;
            // --- stage outputs for the flush wave
            float* row = obuf + (blk & 1) * OB_HALF + (k * 3) * NNP + n;
            row[0 * NNP] = v_;
            row[1 * NNP] = i_;
            row[2 * NNP] = s_;
            // --- barrier, then read the other wave's spv for NEXT step
            sync_lds();
            spvm_pend = spvbuf[par * NN + nm];   // ~120cy, consumed next step
            km_prev = kmir;
        };

        #pragma clang loop unroll(disable)
        for (int blk = 0; blk < NT / CH; ++blk) {
            STEP(0, blk, nb0, eo0, em0);
            STEP(1, blk, nb1, eo1, em1);
            STEP(2, blk, nb2, eo2, em2);
            STEP(3, blk, nb3, eo3, em3);
            STEP(4, blk, nb4, eo4, em4);
            STEP(5, blk, nb5, eo5, em5);
            STEP(6, blk, nb6, eo6, em6);
            STEP(7, blk, nb7, eo7, em7);
        }
    } else {
        // ---------------- flush wave ----------------
        auto flush3 = [&](int h, int tb0, int kk) {
            // half layout [24][NNP]; neuron nn2's 24 dwords are column nn2.
            // stride 129: adjacent nn2-groups hit alternating bank parity -> free
            const float* ob2 = obuf + h * OB_HALF;
            #pragma unroll
            for (int j = 3 * kk; j < 3 * kk + 3; ++j) {
                const int f = j * 64 + l;        // float2 slot 0..1535
                const int nn2 = f / 12;          // neuron
                const int da = 2 * (f - nn2 * 12);
                const float x = ob2[(da    ) * NNP + nn2];
                const float y = ob2[(da + 1) * NNP + nn2];
                *(float2*)(outb + (size_t)nn2 * (NT * 3) + (size_t)tb0 * 3 + da) =
                    make_float2(x, y);
            }
        };
        #pragma clang loop unroll(disable)
        for (int blk = 0; blk < NT / CH; ++blk) {
            #pragma clang loop unroll(disable)
            for (int k = 0; k < CH; ++k) {
                sync_lds();               // match compute waves' per-step barrier
                if (blk > 0) flush3((blk - 1) & 1, (blk - 1) * CH, k);
            }
        }
    }

    // tail: last half-buffer's writes land after the loop's final barrier
    sync_lds();
    if (wid == 2) {
        const float* ob2 = obuf + ((NT / CH - 1) & 1) * OB_HALF;   // half 0
        #pragma unroll
        for (int j = 0; j < 24; ++j) {
            const int f = j * 64 + l;
            const int nn2 = f / 12;
            const int da = 2 * (f - nn2 * 12);
            const float x = ob2[(da    ) * NNP + nn2];
            const float y = ob2[(da + 1) * NNP + nn2];
            *(float2*)(outb + (size_t)nn2 * (NT * 3) + (size_t)(NT - CH) * 3 + da) =
                make_float2(x, y);
        }
    }
}

extern "C" void kernel_launch(void* const* d_in, const int* in_sizes, int n_in,
                              void* d_out, int out_size, void* d_ws, size_t ws_size,
                              hipStream_t stream) {
    const float* w         = (const float*)d_in[0];
    const float* ic        = (const float*)d_in[1];
    const float* v0        = (const float*)d_in[2];
    const float* i0        = (const float*)d_in[3];
    const float* s0        = (const float*)d_in[4];
    const float* mu        = (const float*)d_in[5];
    const float* sigma     = (const float*)d_in[6];
    const float* noise     = (const float*)d_in[7];
    const float* exp_draws = (const float*)d_in[8];
    float* out = (float*)d_out;

    (void)hipFuncSetAttribute((const void*)snn_scan_kernel,
                              hipFuncAttributeMaxDynamicSharedMemorySize,
                              LDS_BYTES);

    snn_scan_kernel<<<dim3(NS), dim3(192), LDS_BYTES, stream>>>(
        w, ic, v0, i0, s0, mu, sigma, noise, exp_draws, out);
}